// Round 14
// baseline (5872.890 us; speedup 1.0000x reference)
//
#include <hip/hip_runtime.h>
#include <hip/hip_bf16.h>

#define D_NODE 300
#define DHID   600
#define NLAYER 5
#define NG     8192
#define BN_EPS 1e-5f
#define KP1    320      // padded K for GEMM1 (300 -> 320)
#define KP2    608      // padded K for GEMM2 (600 -> 608)
#define PER1   (DHID * KP1)    // u16 per W1 plane
#define PER2   (D_NODE * KP2)  // u16 per W2 plane

typedef unsigned short u16;
typedef unsigned long long u64;
using f32x4   = __attribute__((ext_vector_type(4))) float;
using short8  = __attribute__((ext_vector_type(8))) short;
using short4v = __attribute__((ext_vector_type(4))) short;

// ---- bf16 helpers (RNE) ----
__device__ __forceinline__ float bf2f(u16 u) {
    union { unsigned int i; float f; } v; v.i = ((unsigned int)u) << 16; return v.f;
}
__device__ __forceinline__ u16 f2bf(float f) {
    union { float f; unsigned int i; } v; v.f = f;
    unsigned int x = v.i;
    return (u16)((x + 0x7FFFu + ((x >> 16) & 1u)) >> 16);
}

// ---------------- embed ----------------
__global__ __launch_bounds__(256) void embed_kernel(
    const int* __restrict__ an, const int* __restrict__ ct,
    const float* __restrict__ emb_atom, const float* __restrict__ emb_chir,
    u16* __restrict__ h, long total)
{
    long idx = (long)blockIdx.x * blockDim.x + threadIdx.x;
    if (idx >= total) return;
    int n = (int)(idx / 75);
    int c = (int)(idx % 75);
    int a = an[n], cc = ct[n];
    const float4 av = *(const float4*)&emb_atom[(long)a * D_NODE + c * 4];
    const float4 cv = *(const float4*)&emb_chir[(long)cc * D_NODE + c * 4];
    ushort4 o;
    o.x = f2bf(av.x + cv.x);
    o.y = f2bf(av.y + cv.y);
    o.z = f2bf(av.z + cv.z);
    o.w = f2bf(av.w + cv.w);
    *(ushort4*)&h[(long)n * D_NODE + c * 4] = o;
}

// ---- weight convert+split: [L][2][N][KP]; hi = bf16(W), lo = bf16(W - hi) ----
__global__ __launch_bounds__(256) void wconv_split(
    const float* __restrict__ W, u16* __restrict__ WbT,
    int K, int N, int KP, long per, long total)
{
    long idx = (long)blockIdx.x * blockDim.x + threadIdx.x;
    if (idx >= total) return;
    int l = (int)(idx / per);
    long r = idx % per;
    int n = (int)(r / KP);
    int k = (int)(r % KP);
    float v = (k < K) ? W[(long)l * K * N + (long)k * N + n] : 0.f;
    u16 hi = f2bf(v);
    float lo = v - bf2f(hi);
    WbT[(long)(2 * l) * per + r]     = hi;
    WbT[(long)(2 * l + 1) * per + r] = f2bf(lo);
}

// ---------------- CSR build ----------------
__global__ __launch_bounds__(256) void zero_int_kernel(int* __restrict__ p, int n)
{
    int i = blockIdx.x * blockDim.x + threadIdx.x;
    if (i < n) p[i] = 0;
}
__global__ __launch_bounds__(256) void count_kernel(
    const int* __restrict__ dst, int* __restrict__ cnt, int E)
{
    int e = blockIdx.x * blockDim.x + threadIdx.x;
    if (e < E) atomicAdd(&cnt[dst[e]], 1);
}
__global__ __launch_bounds__(256) void scan1_kernel(
    const int* __restrict__ cnt, int* __restrict__ bsum, int N)
{
    __shared__ int red[256];
    int b = blockIdx.x, t = threadIdx.x;
    int i0 = b * 1024 + t * 4;
    int s = 0;
    #pragma unroll
    for (int j = 0; j < 4; ++j) { int i = i0 + j; if (i < N) s += cnt[i]; }
    red[t] = s; __syncthreads();
    for (int off = 128; off > 0; off >>= 1) {
        if (t < off) red[t] += red[t + off];
        __syncthreads();
    }
    if (t == 0) bsum[b] = red[0];
}
__global__ void scan2_kernel(int* __restrict__ bsum, int nb)
{
    if (threadIdx.x == 0 && blockIdx.x == 0) {
        int run = 0;
        for (int b = 0; b < nb; ++b) { int v = bsum[b]; bsum[b] = run; run += v; }
    }
}
__global__ __launch_bounds__(256) void scan3_kernel(
    const int* __restrict__ bsum, int* __restrict__ cnt,
    int* __restrict__ row_ptr, int N, int E)
{
    __shared__ int sbuf[256];
    int b = blockIdx.x, t = threadIdx.x;
    int i0 = b * 1024 + t * 4;
    int v[4]; int s = 0;
    #pragma unroll
    for (int j = 0; j < 4; ++j) { int i = i0 + j; v[j] = (i < N) ? cnt[i] : 0; s += v[j]; }
    sbuf[t] = s; __syncthreads();
    for (int off = 1; off < 256; off <<= 1) {
        int add = (t >= off) ? sbuf[t - off] : 0;
        __syncthreads();
        sbuf[t] += add;
        __syncthreads();
    }
    int base = bsum[b] + sbuf[t] - s;
    #pragma unroll
    for (int j = 0; j < 4; ++j) {
        int i = i0 + j;
        if (i < N) { row_ptr[i] = base; cnt[i] = base; base += v[j]; }
    }
    if (b == 0 && t == 0) row_ptr[N] = E;
}
__global__ __launch_bounds__(256) void fill_kernel(
    const int* __restrict__ dst, int* __restrict__ fillp,
    int* __restrict__ eidx, int E)
{
    int e = blockIdx.x * blockDim.x + threadIdx.x;
    if (e < E) {
        int pos = atomicAdd(&fillp[dst[e]], 1);
        eidx[pos] = e;
    }
}

// ---------------- agg (gather): z[n] = h[n] + sum_in-edges (h[src]+eb+ed) ----------------
// Standalone: 58K blocks of pure TLP hide random-gather latency (R12 proved
// fusing this into the MLP starves it).
__global__ __launch_bounds__(256) void agg_kernel(
    const u16* __restrict__ h,
    const int* __restrict__ src, const int* __restrict__ bt, const int* __restrict__ bd,
    const int* __restrict__ row_ptr, const int* __restrict__ eidx,
    const float* __restrict__ ebond, const float* __restrict__ edir,
    u16* __restrict__ z, long total)
{
    long idx = (long)blockIdx.x * blockDim.x + threadIdx.x;
    if (idx >= total) return;
    int n = (int)(idx / 75);
    int c = (int)(idx % 75);
    const ushort4 hq = *(const ushort4*)&h[(long)n * D_NODE + c * 4];
    float a0 = bf2f(hq.x), a1 = bf2f(hq.y), a2 = bf2f(hq.z), a3 = bf2f(hq.w);
    int s0 = row_ptr[n], s1 = row_ptr[n + 1];
    for (int i = s0; i < s1; ++i) {
        int e = eidx[i];
        int s = src[e], b = bt[e], d = bd[e];
        const ushort4 hv = *(const ushort4*)&h[(long)s * D_NODE + c * 4];
        const float4 eb = *(const float4*)&ebond[(long)b * D_NODE + c * 4];
        const float4 ed = *(const float4*)&edir[(long)d * D_NODE + c * 4];
        a0 += bf2f(hv.x) + eb.x + ed.x;
        a1 += bf2f(hv.y) + eb.y + ed.y;
        a2 += bf2f(hv.z) + eb.z + ed.z;
        a3 += bf2f(hv.w) + eb.w + ed.w;
    }
    ushort4 o;
    o.x = f2bf(a0); o.y = f2bf(a1); o.z = f2bf(a2); o.w = f2bf(a3);
    *(ushort4*)&z[(long)n * D_NODE + c * 4] = o;
}

// ---------------- fused MLP v3: H = BN(relu(Z@W1+b1)@W2+b2) [+relu] ----------------
// nf=4 per wave in phase 1 (32 MFMAs per 4 As-reads -> 2x pipe duty per latency
// window), Tc = 256-col chunks (3 tc passes, 6 barriers), phase 2 = 8-ks run.
// K-order per accumulator unchanged -> bit-identical to R10/R13.
__global__ __launch_bounds__(256, 2) void mlp_fused(
    const u16* __restrict__ Z,
    const u16* __restrict__ W1T,    // [600][320] hi, +PER1 lo
    const u16* __restrict__ W2T,    // [300][608] hi, +PER2 lo
    const float* __restrict__ b1, const float* __restrict__ b2,
    const float* __restrict__ bn_g, const float* __restrict__ bn_b,
    const float* __restrict__ bn_m, const float* __restrict__ bn_v,
    u16* __restrict__ Hout, int Nrows, int relu_out)
{
    __shared__ u16 As[64][328];   // 41,984 B (stride 656B: bank classes rotate/row)
    __shared__ u16 Tc[64][264];   // 33,792 B (stride 528B: rotates too) -> 75,776 total
    const int tid  = threadIdx.x;
    const int lane = tid & 63;
    const int w    = tid >> 6;     // wave 0..3
    const int lrow = lane & 15;
    const int kg   = lane >> 4;    // 0..3
    const long r0  = (long)blockIdx.x * 64;
    const short8 zz = (short8){0,0,0,0,0,0,0,0};

    // stage Z tile: 64 rows x 320 k (zero-padded)
    for (int i = tid; i < 64 * 80; i += 256) {
        int r = i / 80, c4 = i % 80;
        short4v v = (short4v){0, 0, 0, 0};
        if (c4 < 75 && r0 + r < Nrows)
            v = *(const short4v*)&Z[(r0 + r) * D_NODE + c4 * 4];
        *(short4v*)&As[r][c4 * 4] = v;
    }
    __syncthreads();

    f32x4 hacc[4][5];
    #pragma unroll
    for (int m = 0; m < 4; ++m)
        #pragma unroll
        for (int n = 0; n < 5; ++n)
            hacc[m][n] = (f32x4){0.f, 0.f, 0.f, 0.f};

    // W2 per-wave output cols fixed across tc
    const u16* w2p[5]; bool w2v[5];
    #pragma unroll
    for (int nf = 0; nf < 5; ++nf) {
        int gn = w * 80 + nf * 16 + lrow;
        w2v[nf] = (gn < D_NODE);
        w2p[nf] = W2T + (long)gn * KP2 + kg * 8;
    }

    for (int tc = 0; tc < 3; ++tc) {
        // ---- phase 1: T cols [tc*256, +256); this wave: 64 cols (4 nf) ----
        const int cbase = tc * 256 + w * 64;
        const u16* w1p[4]; bool w1v[4];
        #pragma unroll
        for (int nf = 0; nf < 4; ++nf) {
            int gn = cbase + nf * 16 + lrow;
            w1v[nf] = (gn < DHID);
            w1p[nf] = W1T + (long)gn * KP1 + kg * 8;
        }

        f32x4 p1[4][4];
        #pragma unroll
        for (int m = 0; m < 4; ++m)
            #pragma unroll
            for (int nf = 0; nf < 4; ++nf)
                p1[m][nf] = (f32x4){0.f, 0.f, 0.f, 0.f};

        short8 cwh[4], cwl[4];
        #pragma unroll
        for (int nf = 0; nf < 4; ++nf) {
            cwh[nf] = w1v[nf] ? *(const short8*)(w1p[nf])        : zz;
            cwl[nf] = w1v[nf] ? *(const short8*)(w1p[nf] + PER1) : zz;
        }

        #pragma unroll
        for (int k0i = 0; k0i < 10; ++k0i) {
            short8 nwh[4], nwl[4];
            if (k0i < 9) {   // prefetch next k-step's W while this one computes
                const int ko = (k0i + 1) * 32;
                #pragma unroll
                for (int nf = 0; nf < 4; ++nf) {
                    nwh[nf] = w1v[nf] ? *(const short8*)(w1p[nf] + ko)        : zz;
                    nwl[nf] = w1v[nf] ? *(const short8*)(w1p[nf] + PER1 + ko) : zz;
                }
            }
            short8 a0 = *(const short8*)&As[ 0 + lrow][k0i * 32 + kg * 8];
            short8 a1 = *(const short8*)&As[16 + lrow][k0i * 32 + kg * 8];
            short8 a2 = *(const short8*)&As[32 + lrow][k0i * 32 + kg * 8];
            short8 a3 = *(const short8*)&As[48 + lrow][k0i * 32 + kg * 8];

            __builtin_amdgcn_s_setprio(1);
            #pragma unroll
            for (int nf = 0; nf < 4; ++nf) {   // all-hi block (16 independent)
                p1[0][nf] = __builtin_amdgcn_mfma_f32_16x16x32_bf16(a0, cwh[nf], p1[0][nf], 0, 0, 0);
                p1[1][nf] = __builtin_amdgcn_mfma_f32_16x16x32_bf16(a1, cwh[nf], p1[1][nf], 0, 0, 0);
                p1[2][nf] = __builtin_amdgcn_mfma_f32_16x16x32_bf16(a2, cwh[nf], p1[2][nf], 0, 0, 0);
                p1[3][nf] = __builtin_amdgcn_mfma_f32_16x16x32_bf16(a3, cwh[nf], p1[3][nf], 0, 0, 0);
            }
            #pragma unroll
            for (int nf = 0; nf < 4; ++nf) {   // all-lo block (deps 16 apart)
                p1[0][nf] = __builtin_amdgcn_mfma_f32_16x16x32_bf16(a0, cwl[nf], p1[0][nf], 0, 0, 0);
                p1[1][nf] = __builtin_amdgcn_mfma_f32_16x16x32_bf16(a1, cwl[nf], p1[1][nf], 0, 0, 0);
                p1[2][nf] = __builtin_amdgcn_mfma_f32_16x16x32_bf16(a2, cwl[nf], p1[2][nf], 0, 0, 0);
                p1[3][nf] = __builtin_amdgcn_mfma_f32_16x16x32_bf16(a3, cwl[nf], p1[3][nf], 0, 0, 0);
            }
            __builtin_amdgcn_s_setprio(0);

            if (k0i < 9) {
                #pragma unroll
                for (int nf = 0; nf < 4; ++nf) { cwh[nf] = nwh[nf]; cwl[nf] = nwl[nf]; }
            }
        }

        // relu + bias -> Tc (bf16); invalid cols produce 0 (zero W/bias)
        #pragma unroll
        for (int nf = 0; nf < 4; ++nf) {
            int gn = cbase + nf * 16 + lrow;
            float bias = w1v[nf] ? b1[gn] : 0.f;
            #pragma unroll
            for (int m = 0; m < 4; ++m)
                #pragma unroll
                for (int j = 0; j < 4; ++j) {
                    float v = fmaxf(p1[m][nf][j] + bias, 0.f);
                    Tc[m * 16 + kg * 4 + j][w * 64 + nf * 16 + lrow] = f2bf(v);
                }
        }
        __syncthreads();

        // ---- phase 2: hacc += Tc @ W2[k = tc*256 ...]; this wave: 80 out cols ----
        const int kbase = tc * 256;
        int ksmax = (KP2 - kbase + 31) / 32;
        if (ksmax > 8) ksmax = 8;

        short8 w2h[5], w2l[5];
        #pragma unroll
        for (int nf = 0; nf < 5; ++nf) {
            w2h[nf] = w2v[nf] ? *(const short8*)(w2p[nf] + kbase)        : zz;
            w2l[nf] = w2v[nf] ? *(const short8*)(w2p[nf] + PER2 + kbase) : zz;
        }

        for (int ks = 0; ks < ksmax; ++ks) {
            short8 w2hn[5], w2ln[5];
            const bool pf = (ks + 1 < ksmax);
            if (pf) {
                const int ko = kbase + (ks + 1) * 32;
                #pragma unroll
                for (int nf = 0; nf < 5; ++nf) {
                    w2hn[nf] = w2v[nf] ? *(const short8*)(w2p[nf] + ko)        : zz;
                    w2ln[nf] = w2v[nf] ? *(const short8*)(w2p[nf] + PER2 + ko) : zz;
                }
            }
            short8 t0 = *(const short8*)&Tc[ 0 + lrow][ks * 32 + kg * 8];
            short8 t1 = *(const short8*)&Tc[16 + lrow][ks * 32 + kg * 8];
            short8 t2 = *(const short8*)&Tc[32 + lrow][ks * 32 + kg * 8];
            short8 t3 = *(const short8*)&Tc[48 + lrow][ks * 32 + kg * 8];
            __builtin_amdgcn_s_setprio(1);
            #pragma unroll
            for (int nf = 0; nf < 5; ++nf) {
                hacc[0][nf] = __builtin_amdgcn_mfma_f32_16x16x32_bf16(t0, w2h[nf], hacc[0][nf], 0, 0, 0);
                hacc[1][nf] = __builtin_amdgcn_mfma_f32_16x16x32_bf16(t1, w2h[nf], hacc[1][nf], 0, 0, 0);
                hacc[2][nf] = __builtin_amdgcn_mfma_f32_16x16x32_bf16(t2, w2h[nf], hacc[2][nf], 0, 0, 0);
                hacc[3][nf] = __builtin_amdgcn_mfma_f32_16x16x32_bf16(t3, w2h[nf], hacc[3][nf], 0, 0, 0);
            }
            #pragma unroll
            for (int nf = 0; nf < 5; ++nf) {
                hacc[0][nf] = __builtin_amdgcn_mfma_f32_16x16x32_bf16(t0, w2l[nf], hacc[0][nf], 0, 0, 0);
                hacc[1][nf] = __builtin_amdgcn_mfma_f32_16x16x32_bf16(t1, w2l[nf], hacc[1][nf], 0, 0, 0);
                hacc[2][nf] = __builtin_amdgcn_mfma_f32_16x16x32_bf16(t2, w2l[nf], hacc[2][nf], 0, 0, 0);
                hacc[3][nf] = __builtin_amdgcn_mfma_f32_16x16x32_bf16(t3, w2l[nf], hacc[3][nf], 0, 0, 0);
            }
            __builtin_amdgcn_s_setprio(0);
            if (pf) {
                #pragma unroll
                for (int nf = 0; nf < 5; ++nf) { w2h[nf] = w2hn[nf]; w2l[nf] = w2ln[nf]; }
            }
        }
        __syncthreads();   // Tc consumed; next chunk may overwrite
    }

    // epilogue: bias + BN (+relu), store bf16
    #pragma unroll
    for (int nf = 0; nf < 5; ++nf) {
        int gn = w * 80 + nf * 16 + lrow;
        if (gn < D_NODE) {
            float bias = b2[gn];
            float sc = bn_g[gn] * rsqrtf(bn_v[gn] + BN_EPS);
            float mn = bn_m[gn], bb = bn_b[gn];
            #pragma unroll
            for (int m = 0; m < 4; ++m)
                #pragma unroll
                for (int j = 0; j < 4; ++j) {
                    long gr = r0 + m * 16 + kg * 4 + j;
                    if (gr < Nrows) {
                        float v = hacc[m][nf][j] + bias;
                        v = (v - mn) * sc + bb;
                        if (relu_out) v = fmaxf(v, 0.f);
                        Hout[gr * D_NODE + gn] = f2bf(v);
                    }
                }
        }
    }
}

// ---------------- fused pool (sorted gid) + Linear(300,256) ----------------
__device__ __forceinline__ int lower_bound(const int* __restrict__ a, int n, int key)
{
    int lo = 0, hi = n;
    while (lo < hi) { int mid = (lo + hi) >> 1; if (a[mid] < key) lo = mid + 1; else hi = mid; }
    return lo;
}

__global__ __launch_bounds__(256) void pool_head1(
    const u16* __restrict__ h, const int* __restrict__ gid, int N,
    const float* __restrict__ Wt, const float* __restrict__ bt,
    float* __restrict__ x1)
{
    __shared__ float xs[304];
    __shared__ int se[2];
    int g = blockIdx.x;
    int t = threadIdx.x;
    if (t == 0) se[0] = lower_bound(gid, N, g);
    if (t == 1) se[1] = lower_bound(gid, N, g + 1);
    __syncthreads();
    int start = se[0], end = se[1];
    float inv = (end > start) ? 1.0f / (float)(end - start) : 0.f;
    float a0 = 0.f, a1 = 0.f;
    for (int n = start; n < end; ++n) {
        const u16* hp = &h[(long)n * D_NODE];
        a0 += bf2f(hp[t]);
        if (t < 44) a1 += bf2f(hp[256 + t]);
    }
    xs[t] = a0 * inv;
    if (t < 44) xs[256 + t] = a1 * inv;
    __syncthreads();
    float acc = bt[t];
    for (int k = 0; k < D_NODE; ++k)
        acc = fmaf(xs[k], Wt[(long)k * 256 + t], acc);
    x1[(long)g * 256 + t] = acc;
}

// ---------------- head 2: Linear(256,128)+leaky, Linear(128,1) ----------------
__global__ __launch_bounds__(128) void head2_kernel(
    const float* __restrict__ x1,
    const float* __restrict__ Wh, const float* __restrict__ bh,
    const float* __restrict__ Wf, const float* __restrict__ bf,
    float* __restrict__ out, int G)
{
    __shared__ float xs[256];
    __shared__ float red[128];
    int g = blockIdx.x;
    int t = threadIdx.x;
    for (int i = t; i < 256; i += 128) xs[i] = x1[(long)g * 256 + i];
    __syncthreads();
    float acc = bh[t];
    for (int k = 0; k < 256; ++k)
        acc = fmaf(xs[k], Wh[(long)k * 128 + t], acc);
    acc = acc > 0.f ? acc : 0.01f * acc;
    red[t] = acc * Wf[t];
    __syncthreads();
    for (int s = 64; s > 0; s >>= 1) {
        if (t < s) red[t] += red[t + s];
        __syncthreads();
    }
    if (t == 0) out[g] = red[0] + bf[0];
}

extern "C" void kernel_launch(void* const* d_in, const int* in_sizes, int n_in,
                              void* d_out, int out_size, void* d_ws, size_t ws_size,
                              hipStream_t stream)
{
    const int* an   = (const int*)d_in[0];
    const int* ct   = (const int*)d_in[1];
    const int* bt   = (const int*)d_in[2];
    const int* bd   = (const int*)d_in[3];
    const int* src  = (const int*)d_in[4];
    const int* dst  = (const int*)d_in[5];
    const int* gid  = (const int*)d_in[6];
    const float* emb_atom  = (const float*)d_in[8];
    const float* emb_chir  = (const float*)d_in[9];
    const float* edge_bond = (const float*)d_in[10];
    const float* edge_dir  = (const float*)d_in[11];
    const float* W1   = (const float*)d_in[12];
    const float* b1   = (const float*)d_in[13];
    const float* W2   = (const float*)d_in[14];
    const float* b2   = (const float*)d_in[15];
    const float* bn_g = (const float*)d_in[16];
    const float* bn_b = (const float*)d_in[17];
    const float* bn_m = (const float*)d_in[18];
    const float* bn_v = (const float*)d_in[19];
    const float* Wt   = (const float*)d_in[20];
    const float* btr  = (const float*)d_in[21];
    const float* Wh   = (const float*)d_in[22];
    const float* bh   = (const float*)d_in[23];
    const float* Wf   = (const float*)d_in[24];
    const float* bf   = (const float*)d_in[25];

    const long N = in_sizes[0];
    const long E = in_sizes[4];
    const int  G = NG;

    // ---- workspace (~249 MB): h | z | WbT1 | WbT2 | row_ptr | eidx ----
    char* base = (char*)d_ws;
    size_t off = 0;
    u16* h  = (u16*)(base + off);           off += (size_t)N * D_NODE * 2;
    u16* z  = (u16*)(base + off);           off += (size_t)N * D_NODE * 2;
    u16* WbT1 = (u16*)(base + off);         off += (size_t)NLAYER * 2 * PER1 * 2;
    u16* WbT2 = (u16*)(base + off);         off += (size_t)NLAYER * 2 * PER2 * 2;
    int* row_ptr = (int*)(base + off);      off += (((size_t)(N + 1) * 4) + 63) & ~(size_t)63;
    int* eidx = (int*)(base + off);
    // aliases into z (disjoint lifetimes: CSR build pre-embed; x1 post-layers)
    int* row_fill = (int*)z;
    int* bsum     = row_fill + N;
    float* x1     = (float*)z;

    const long nodeTot = N * 75;
    const int  blk = 256;
    const long nodeBlocks = (nodeTot + blk - 1) / blk;
    const int  SB = (int)((N + 1023) / 1024);

    // weights -> split bf16 (hi+lo), transposed, K-padded
    {
        long t1 = (long)NLAYER * PER1;
        wconv_split<<<(t1 + blk - 1) / blk, blk, 0, stream>>>(
            W1, WbT1, D_NODE, DHID, KP1, (long)PER1, t1);
        long t2 = (long)NLAYER * PER2;
        wconv_split<<<(t2 + blk - 1) / blk, blk, 0, stream>>>(
            W2, WbT2, DHID, D_NODE, KP2, (long)PER2, t2);
    }

    // CSR build (graph static across layers)
    zero_int_kernel<<<((int)N + blk - 1) / blk, blk, 0, stream>>>(row_fill, (int)N);
    count_kernel<<<((int)E + blk - 1) / blk, blk, 0, stream>>>(dst, row_fill, (int)E);
    scan1_kernel<<<SB, blk, 0, stream>>>(row_fill, bsum, (int)N);
    scan2_kernel<<<1, 64, 0, stream>>>(bsum, SB);
    scan3_kernel<<<SB, blk, 0, stream>>>(bsum, row_fill, row_ptr, (int)N, (int)E);
    fill_kernel<<<((int)E + blk - 1) / blk, blk, 0, stream>>>(dst, row_fill, eidx, (int)E);

    embed_kernel<<<nodeBlocks, blk, 0, stream>>>(an, ct, emb_atom, emb_chir, h, nodeTot);

    const int mlpBlocks = (int)((N + 63) / 64);
    for (int l = 0; l < NLAYER; ++l) {
        agg_kernel<<<nodeBlocks, blk, 0, stream>>>(
            h, src, bt, bd, row_ptr, eidx,
            edge_bond + (long)l * 6 * D_NODE,
            edge_dir  + (long)l * 3 * D_NODE,
            z, nodeTot);

        mlp_fused<<<mlpBlocks, 256, 0, stream>>>(
            z,
            WbT1 + (long)(2 * l) * PER1,
            WbT2 + (long)(2 * l) * PER2,
            b1 + (long)l * DHID, b2 + (long)l * D_NODE,
            bn_g + (long)l * D_NODE, bn_b + (long)l * D_NODE,
            bn_m + (long)l * D_NODE, bn_v + (long)l * D_NODE,
            h, (int)N, (l < NLAYER - 1) ? 1 : 0);
    }

    pool_head1<<<G, 256, 0, stream>>>(h, gid, (int)N, Wt, btr, x1);
    head2_kernel<<<G, 128, 0, stream>>>(x1, Wh, bh, Wf, bf, (float*)d_out, G);
}

// Round 15
// 4237.082 us; speedup vs baseline: 1.3861x; 1.3861x over previous
//
#include <hip/hip_runtime.h>
#include <hip/hip_bf16.h>

#define D_NODE 300
#define DHID   600
#define NLAYER 5
#define NG     8192
#define BN_EPS 1e-5f
#define KP1    320      // padded K for GEMM1 (300 -> 320)
#define KP2    608      // padded K for GEMM2 (600 -> 608)
#define PER1   (DHID * KP1)    // u16 per W1 plane
#define PER2   (D_NODE * KP2)  // u16 per W2 plane

typedef unsigned short u16;
typedef unsigned long long u64;
using f32x4   = __attribute__((ext_vector_type(4))) float;
using short8  = __attribute__((ext_vector_type(8))) short;
using short4v = __attribute__((ext_vector_type(4))) short;

// ---- bf16 helpers (RNE) ----
__device__ __forceinline__ float bf2f(u16 u) {
    union { unsigned int i; float f; } v; v.i = ((unsigned int)u) << 16; return v.f;
}
__device__ __forceinline__ u16 f2bf(float f) {
    union { float f; unsigned int i; } v; v.f = f;
    unsigned int x = v.i;
    return (u16)((x + 0x7FFFu + ((x >> 16) & 1u)) >> 16);
}

// ---------------- embed ----------------
__global__ __launch_bounds__(256) void embed_kernel(
    const int* __restrict__ an, const int* __restrict__ ct,
    const float* __restrict__ emb_atom, const float* __restrict__ emb_chir,
    u16* __restrict__ h, long total)
{
    long idx = (long)blockIdx.x * blockDim.x + threadIdx.x;
    if (idx >= total) return;
    int n = (int)(idx / 75);
    int c = (int)(idx % 75);
    int a = an[n], cc = ct[n];
    const float4 av = *(const float4*)&emb_atom[(long)a * D_NODE + c * 4];
    const float4 cv = *(const float4*)&emb_chir[(long)cc * D_NODE + c * 4];
    ushort4 o;
    o.x = f2bf(av.x + cv.x);
    o.y = f2bf(av.y + cv.y);
    o.z = f2bf(av.z + cv.z);
    o.w = f2bf(av.w + cv.w);
    *(ushort4*)&h[(long)n * D_NODE + c * 4] = o;
}

// ---- weight convert+split: [L][2][N][KP]; hi = bf16(W), lo = bf16(W - hi) ----
__global__ __launch_bounds__(256) void wconv_split(
    const float* __restrict__ W, u16* __restrict__ WbT,
    int K, int N, int KP, long per, long total)
{
    long idx = (long)blockIdx.x * blockDim.x + threadIdx.x;
    if (idx >= total) return;
    int l = (int)(idx / per);
    long r = idx % per;
    int n = (int)(r / KP);
    int k = (int)(r % KP);
    float v = (k < K) ? W[(long)l * K * N + (long)k * N + n] : 0.f;
    u16 hi = f2bf(v);
    float lo = v - bf2f(hi);
    WbT[(long)(2 * l) * per + r]     = hi;
    WbT[(long)(2 * l + 1) * per + r] = f2bf(lo);
}

// ---------------- CSR build ----------------
__global__ __launch_bounds__(256) void zero_int_kernel(int* __restrict__ p, int n)
{
    int i = blockIdx.x * blockDim.x + threadIdx.x;
    if (i < n) p[i] = 0;
}
__global__ __launch_bounds__(256) void count_kernel(
    const int* __restrict__ dst, int* __restrict__ cnt, int E)
{
    int e = blockIdx.x * blockDim.x + threadIdx.x;
    if (e < E) atomicAdd(&cnt[dst[e]], 1);
}
__global__ __launch_bounds__(256) void scan1_kernel(
    const int* __restrict__ cnt, int* __restrict__ bsum, int N)
{
    __shared__ int red[256];
    int b = blockIdx.x, t = threadIdx.x;
    int i0 = b * 1024 + t * 4;
    int s = 0;
    #pragma unroll
    for (int j = 0; j < 4; ++j) { int i = i0 + j; if (i < N) s += cnt[i]; }
    red[t] = s; __syncthreads();
    for (int off = 128; off > 0; off >>= 1) {
        if (t < off) red[t] += red[t + off];
        __syncthreads();
    }
    if (t == 0) bsum[b] = red[0];
}
__global__ void scan2_kernel(int* __restrict__ bsum, int nb)
{
    if (threadIdx.x == 0 && blockIdx.x == 0) {
        int run = 0;
        for (int b = 0; b < nb; ++b) { int v = bsum[b]; bsum[b] = run; run += v; }
    }
}
__global__ __launch_bounds__(256) void scan3_kernel(
    const int* __restrict__ bsum, int* __restrict__ cnt,
    int* __restrict__ row_ptr, int N, int E)
{
    __shared__ int sbuf[256];
    int b = blockIdx.x, t = threadIdx.x;
    int i0 = b * 1024 + t * 4;
    int v[4]; int s = 0;
    #pragma unroll
    for (int j = 0; j < 4; ++j) { int i = i0 + j; v[j] = (i < N) ? cnt[i] : 0; s += v[j]; }
    sbuf[t] = s; __syncthreads();
    for (int off = 1; off < 256; off <<= 1) {
        int add = (t >= off) ? sbuf[t - off] : 0;
        __syncthreads();
        sbuf[t] += add;
        __syncthreads();
    }
    int base = bsum[b] + sbuf[t] - s;
    #pragma unroll
    for (int j = 0; j < 4; ++j) {
        int i = i0 + j;
        if (i < N) { row_ptr[i] = base; cnt[i] = base; base += v[j]; }
    }
    if (b == 0 && t == 0) row_ptr[N] = E;
}
__global__ __launch_bounds__(256) void fill_kernel(
    const int* __restrict__ dst, int* __restrict__ fillp,
    int* __restrict__ eidx, int E)
{
    int e = blockIdx.x * blockDim.x + threadIdx.x;
    if (e < E) {
        int pos = atomicAdd(&fillp[dst[e]], 1);
        eidx[pos] = e;
    }
}

// ---------------- agg (gather): z[n] = h[n] + sum_in-edges (h[src]+eb+ed) ----------------
// Standalone: 58K blocks of pure TLP hide random-gather latency (R12 proved
// fusing this into the MLP starves it).
__global__ __launch_bounds__(256) void agg_kernel(
    const u16* __restrict__ h,
    const int* __restrict__ src, const int* __restrict__ bt, const int* __restrict__ bd,
    const int* __restrict__ row_ptr, const int* __restrict__ eidx,
    const float* __restrict__ ebond, const float* __restrict__ edir,
    u16* __restrict__ z, long total)
{
    long idx = (long)blockIdx.x * blockDim.x + threadIdx.x;
    if (idx >= total) return;
    int n = (int)(idx / 75);
    int c = (int)(idx % 75);
    const ushort4 hq = *(const ushort4*)&h[(long)n * D_NODE + c * 4];
    float a0 = bf2f(hq.x), a1 = bf2f(hq.y), a2 = bf2f(hq.z), a3 = bf2f(hq.w);
    int s0 = row_ptr[n], s1 = row_ptr[n + 1];
    for (int i = s0; i < s1; ++i) {
        int e = eidx[i];
        int s = src[e], b = bt[e], d = bd[e];
        const ushort4 hv = *(const ushort4*)&h[(long)s * D_NODE + c * 4];
        const float4 eb = *(const float4*)&ebond[(long)b * D_NODE + c * 4];
        const float4 ed = *(const float4*)&edir[(long)d * D_NODE + c * 4];
        a0 += bf2f(hv.x) + eb.x + ed.x;
        a1 += bf2f(hv.y) + eb.y + ed.y;
        a2 += bf2f(hv.z) + eb.z + ed.z;
        a3 += bf2f(hv.w) + eb.w + ed.w;
    }
    ushort4 o;
    o.x = f2bf(a0); o.y = f2bf(a1); o.z = f2bf(a2); o.w = f2bf(a3);
    *(ushort4*)&z[(long)n * D_NODE + c * 4] = o;
}

// ---------------- fused MLP v4: R10 geometry + pipelined fragment reads ----------------
// nf=2, Tc=128 (R10 = best measured). NEW: ds_read a/t-fragments for k-step
// n+1 issued during step n's MFMAs (W was already prefetched; the exposed
// ~120cy LDS latency per k-step was the remaining uncovered stall).
// Per-accumulator math order unchanged -> bit-identical to R10.
__global__ __launch_bounds__(256, 2) void mlp_fused(
    const u16* __restrict__ Z,
    const u16* __restrict__ W1T,    // [600][320] hi, +PER1 lo
    const u16* __restrict__ W2T,    // [300][608] hi, +PER2 lo
    const float* __restrict__ b1, const float* __restrict__ b2,
    const float* __restrict__ bn_g, const float* __restrict__ bn_b,
    const float* __restrict__ bn_m, const float* __restrict__ bn_v,
    u16* __restrict__ Hout, int Nrows, int relu_out)
{
    __shared__ u16 As[64][328];   // 41,984 B
    __shared__ u16 Tc[64][136];   // 17,408 B  (59,392 total = R10)
    const int tid  = threadIdx.x;
    const int lane = tid & 63;
    const int w    = tid >> 6;     // wave 0..3
    const int lrow = lane & 15;
    const int kg   = lane >> 4;    // 0..3
    const long r0  = (long)blockIdx.x * 64;
    const short8 zz = (short8){0,0,0,0,0,0,0,0};

    // stage Z tile: 64 rows x 320 k (zero-padded)
    for (int i = tid; i < 64 * 80; i += 256) {
        int r = i / 80, c4 = i % 80;
        short4v v = (short4v){0, 0, 0, 0};
        if (c4 < 75 && r0 + r < Nrows)
            v = *(const short4v*)&Z[(r0 + r) * D_NODE + c4 * 4];
        *(short4v*)&As[r][c4 * 4] = v;
    }
    __syncthreads();

    f32x4 hacc[4][5];
    #pragma unroll
    for (int m = 0; m < 4; ++m)
        #pragma unroll
        for (int n = 0; n < 5; ++n)
            hacc[m][n] = (f32x4){0.f, 0.f, 0.f, 0.f};

    // W2 per-wave output cols fixed across tc
    const u16* w2p[5]; bool w2v[5];
    #pragma unroll
    for (int nf = 0; nf < 5; ++nf) {
        int gn = w * 80 + nf * 16 + lrow;
        w2v[nf] = (gn < D_NODE);
        w2p[nf] = W2T + (long)gn * KP2 + kg * 8;
    }

    for (int tc = 0; tc < 5; ++tc) {
        const int c0 = tc * 128 + w * 32;

        // ---- phase 1: T chunk cols [tc*128, +128); this wave: 32 cols ----
        const u16* w1p[2]; bool w1v[2];
        #pragma unroll
        for (int nf = 0; nf < 2; ++nf) {
            int gn = c0 + nf * 16 + lrow;
            w1v[nf] = (gn < DHID);
            w1p[nf] = W1T + (long)gn * KP1 + kg * 8;
        }
        f32x4 p1[4][2];
        #pragma unroll
        for (int m = 0; m < 4; ++m)
            #pragma unroll
            for (int n = 0; n < 2; ++n)
                p1[m][n] = (f32x4){0.f, 0.f, 0.f, 0.f};

        short8 cwh0 = w1v[0] ? *(const short8*)(w1p[0])        : zz;
        short8 cwl0 = w1v[0] ? *(const short8*)(w1p[0] + PER1) : zz;
        short8 cwh1 = w1v[1] ? *(const short8*)(w1p[1])        : zz;
        short8 cwl1 = w1v[1] ? *(const short8*)(w1p[1] + PER1) : zz;
        // initial a-frags (k-step 0)
        short8 a0 = *(const short8*)&As[ 0 + lrow][kg * 8];
        short8 a1 = *(const short8*)&As[16 + lrow][kg * 8];
        short8 a2 = *(const short8*)&As[32 + lrow][kg * 8];
        short8 a3 = *(const short8*)&As[48 + lrow][kg * 8];

        #pragma unroll
        for (int k0i = 0; k0i < 10; ++k0i) {
            short8 nwh0, nwl0, nwh1, nwl1, na0, na1, na2, na3;
            if (k0i < 9) {   // prefetch next k-step: W (global) AND a-frags (LDS)
                const int ko = (k0i + 1) * 32;
                nwh0 = w1v[0] ? *(const short8*)(w1p[0] + ko)        : zz;
                nwl0 = w1v[0] ? *(const short8*)(w1p[0] + PER1 + ko) : zz;
                nwh1 = w1v[1] ? *(const short8*)(w1p[1] + ko)        : zz;
                nwl1 = w1v[1] ? *(const short8*)(w1p[1] + PER1 + ko) : zz;
                na0 = *(const short8*)&As[ 0 + lrow][ko + kg * 8];
                na1 = *(const short8*)&As[16 + lrow][ko + kg * 8];
                na2 = *(const short8*)&As[32 + lrow][ko + kg * 8];
                na3 = *(const short8*)&As[48 + lrow][ko + kg * 8];
            }

            __builtin_amdgcn_s_setprio(1);
            // all-hi (8 independent), then all-lo (deps 8 apart)
            p1[0][0] = __builtin_amdgcn_mfma_f32_16x16x32_bf16(a0, cwh0, p1[0][0], 0, 0, 0);
            p1[1][0] = __builtin_amdgcn_mfma_f32_16x16x32_bf16(a1, cwh0, p1[1][0], 0, 0, 0);
            p1[2][0] = __builtin_amdgcn_mfma_f32_16x16x32_bf16(a2, cwh0, p1[2][0], 0, 0, 0);
            p1[3][0] = __builtin_amdgcn_mfma_f32_16x16x32_bf16(a3, cwh0, p1[3][0], 0, 0, 0);
            p1[0][1] = __builtin_amdgcn_mfma_f32_16x16x32_bf16(a0, cwh1, p1[0][1], 0, 0, 0);
            p1[1][1] = __builtin_amdgcn_mfma_f32_16x16x32_bf16(a1, cwh1, p1[1][1], 0, 0, 0);
            p1[2][1] = __builtin_amdgcn_mfma_f32_16x16x32_bf16(a2, cwh1, p1[2][1], 0, 0, 0);
            p1[3][1] = __builtin_amdgcn_mfma_f32_16x16x32_bf16(a3, cwh1, p1[3][1], 0, 0, 0);
            p1[0][0] = __builtin_amdgcn_mfma_f32_16x16x32_bf16(a0, cwl0, p1[0][0], 0, 0, 0);
            p1[1][0] = __builtin_amdgcn_mfma_f32_16x16x32_bf16(a1, cwl0, p1[1][0], 0, 0, 0);
            p1[2][0] = __builtin_amdgcn_mfma_f32_16x16x32_bf16(a2, cwl0, p1[2][0], 0, 0, 0);
            p1[3][0] = __builtin_amdgcn_mfma_f32_16x16x32_bf16(a3, cwl0, p1[3][0], 0, 0, 0);
            p1[0][1] = __builtin_amdgcn_mfma_f32_16x16x32_bf16(a0, cwl1, p1[0][1], 0, 0, 0);
            p1[1][1] = __builtin_amdgcn_mfma_f32_16x16x32_bf16(a1, cwl1, p1[1][1], 0, 0, 0);
            p1[2][1] = __builtin_amdgcn_mfma_f32_16x16x32_bf16(a2, cwl1, p1[2][1], 0, 0, 0);
            p1[3][1] = __builtin_amdgcn_mfma_f32_16x16x32_bf16(a3, cwl1, p1[3][1], 0, 0, 0);
            __builtin_amdgcn_s_setprio(0);

            if (k0i < 9) {
                cwh0 = nwh0; cwl0 = nwl0; cwh1 = nwh1; cwl1 = nwl1;
                a0 = na0; a1 = na1; a2 = na2; a3 = na3;
            }
        }

        // relu + bias -> Tc (bf16). Cols with gn>=600 get 0 (zero W1/bias).
        #pragma unroll
        for (int nf = 0; nf < 2; ++nf) {
            int gn = c0 + nf * 16 + lrow;
            float bias = w1v[nf] ? b1[gn] : 0.f;
            #pragma unroll
            for (int m = 0; m < 4; ++m)
                #pragma unroll
                for (int j = 0; j < 4; ++j) {
                    float v = fmaxf(p1[m][nf][j] + bias, 0.f);
                    Tc[m * 16 + kg * 4 + j][w * 32 + nf * 16 + lrow] = f2bf(v);
                }
        }
        __syncthreads();

        // ---- phase 2: hacc += Tc @ W2[k = tc*128 ...]; this wave: 80 out cols ----
        const int kbase = tc * 128;
        short8 w2h[5], w2l[5];
        #pragma unroll
        for (int nf = 0; nf < 5; ++nf) {
            w2h[nf] = w2v[nf] ? *(const short8*)(w2p[nf] + kbase)        : zz;
            w2l[nf] = w2v[nf] ? *(const short8*)(w2p[nf] + PER2 + kbase) : zz;
        }
        // initial t-frags (ks=0)
        short8 t0 = *(const short8*)&Tc[ 0 + lrow][kg * 8];
        short8 t1 = *(const short8*)&Tc[16 + lrow][kg * 8];
        short8 t2 = *(const short8*)&Tc[32 + lrow][kg * 8];
        short8 t3 = *(const short8*)&Tc[48 + lrow][kg * 8];

        #pragma unroll
        for (int ks = 0; ks < 4; ++ks) {
            short8 w2hn[5], w2ln[5], nt0, nt1, nt2, nt3;
            const bool pf = (ks < 3) && (kbase + (ks + 1) * 32 < KP2);
            if (pf) {
                const int ko = kbase + (ks + 1) * 32;
                #pragma unroll
                for (int nf = 0; nf < 5; ++nf) {
                    w2hn[nf] = w2v[nf] ? *(const short8*)(w2p[nf] + ko)        : zz;
                    w2ln[nf] = w2v[nf] ? *(const short8*)(w2p[nf] + PER2 + ko) : zz;
                }
                nt0 = *(const short8*)&Tc[ 0 + lrow][(ks + 1) * 32 + kg * 8];
                nt1 = *(const short8*)&Tc[16 + lrow][(ks + 1) * 32 + kg * 8];
                nt2 = *(const short8*)&Tc[32 + lrow][(ks + 1) * 32 + kg * 8];
                nt3 = *(const short8*)&Tc[48 + lrow][(ks + 1) * 32 + kg * 8];
            }
            if (kbase + ks * 32 < KP2) {    // current k-step valid (k < 608)
                __builtin_amdgcn_s_setprio(1);
                #pragma unroll
                for (int nf = 0; nf < 5; ++nf) {
                    hacc[0][nf] = __builtin_amdgcn_mfma_f32_16x16x32_bf16(t0, w2h[nf], hacc[0][nf], 0, 0, 0);
                    hacc[1][nf] = __builtin_amdgcn_mfma_f32_16x16x32_bf16(t1, w2h[nf], hacc[1][nf], 0, 0, 0);
                    hacc[2][nf] = __builtin_amdgcn_mfma_f32_16x16x32_bf16(t2, w2h[nf], hacc[2][nf], 0, 0, 0);
                    hacc[3][nf] = __builtin_amdgcn_mfma_f32_16x16x32_bf16(t3, w2h[nf], hacc[3][nf], 0, 0, 0);
                }
                #pragma unroll
                for (int nf = 0; nf < 5; ++nf) {
                    hacc[0][nf] = __builtin_amdgcn_mfma_f32_16x16x32_bf16(t0, w2l[nf], hacc[0][nf], 0, 0, 0);
                    hacc[1][nf] = __builtin_amdgcn_mfma_f32_16x16x32_bf16(t1, w2l[nf], hacc[1][nf], 0, 0, 0);
                    hacc[2][nf] = __builtin_amdgcn_mfma_f32_16x16x32_bf16(t2, w2l[nf], hacc[2][nf], 0, 0, 0);
                    hacc[3][nf] = __builtin_amdgcn_mfma_f32_16x16x32_bf16(t3, w2l[nf], hacc[3][nf], 0, 0, 0);
                }
                __builtin_amdgcn_s_setprio(0);
            }
            if (pf) {
                #pragma unroll
                for (int nf = 0; nf < 5; ++nf) { w2h[nf] = w2hn[nf]; w2l[nf] = w2ln[nf]; }
                t0 = nt0; t1 = nt1; t2 = nt2; t3 = nt3;
            }
        }
        __syncthreads();   // Tc consumed; next chunk may overwrite
    }

    // epilogue: bias + BN (+relu), store bf16
    #pragma unroll
    for (int nf = 0; nf < 5; ++nf) {
        int gn = w * 80 + nf * 16 + lrow;
        if (gn < D_NODE) {
            float bias = b2[gn];
            float sc = bn_g[gn] * rsqrtf(bn_v[gn] + BN_EPS);
            float mn = bn_m[gn], bb = bn_b[gn];
            #pragma unroll
            for (int m = 0; m < 4; ++m)
                #pragma unroll
                for (int j = 0; j < 4; ++j) {
                    long gr = r0 + m * 16 + kg * 4 + j;
                    if (gr < Nrows) {
                        float v = hacc[m][nf][j] + bias;
                        v = (v - mn) * sc + bb;
                        if (relu_out) v = fmaxf(v, 0.f);
                        Hout[gr * D_NODE + gn] = f2bf(v);
                    }
                }
        }
    }
}

// ---------------- fused pool (sorted gid) + Linear(300,256) ----------------
__device__ __forceinline__ int lower_bound(const int* __restrict__ a, int n, int key)
{
    int lo = 0, hi = n;
    while (lo < hi) { int mid = (lo + hi) >> 1; if (a[mid] < key) lo = mid + 1; else hi = mid; }
    return lo;
}

__global__ __launch_bounds__(256) void pool_head1(
    const u16* __restrict__ h, const int* __restrict__ gid, int N,
    const float* __restrict__ Wt, const float* __restrict__ bt,
    float* __restrict__ x1)
{
    __shared__ float xs[304];
    __shared__ int se[2];
    int g = blockIdx.x;
    int t = threadIdx.x;
    if (t == 0) se[0] = lower_bound(gid, N, g);
    if (t == 1) se[1] = lower_bound(gid, N, g + 1);
    __syncthreads();
    int start = se[0], end = se[1];
    float inv = (end > start) ? 1.0f / (float)(end - start) : 0.f;
    float a0 = 0.f, a1 = 0.f;
    for (int n = start; n < end; ++n) {
        const u16* hp = &h[(long)n * D_NODE];
        a0 += bf2f(hp[t]);
        if (t < 44) a1 += bf2f(hp[256 + t]);
    }
    xs[t] = a0 * inv;
    if (t < 44) xs[256 + t] = a1 * inv;
    __syncthreads();
    float acc = bt[t];
    for (int k = 0; k < D_NODE; ++k)
        acc = fmaf(xs[k], Wt[(long)k * 256 + t], acc);
    x1[(long)g * 256 + t] = acc;
}

// ---------------- head 2: Linear(256,128)+leaky, Linear(128,1) ----------------
__global__ __launch_bounds__(128) void head2_kernel(
    const float* __restrict__ x1,
    const float* __restrict__ Wh, const float* __restrict__ bh,
    const float* __restrict__ Wf, const float* __restrict__ bf,
    float* __restrict__ out, int G)
{
    __shared__ float xs[256];
    __shared__ float red[128];
    int g = blockIdx.x;
    int t = threadIdx.x;
    for (int i = t; i < 256; i += 128) xs[i] = x1[(long)g * 256 + i];
    __syncthreads();
    float acc = bh[t];
    for (int k = 0; k < 256; ++k)
        acc = fmaf(xs[k], Wh[(long)k * 128 + t], acc);
    acc = acc > 0.f ? acc : 0.01f * acc;
    red[t] = acc * Wf[t];
    __syncthreads();
    for (int s = 64; s > 0; s >>= 1) {
        if (t < s) red[t] += red[t + s];
        __syncthreads();
    }
    if (t == 0) out[g] = red[0] + bf[0];
}

extern "C" void kernel_launch(void* const* d_in, const int* in_sizes, int n_in,
                              void* d_out, int out_size, void* d_ws, size_t ws_size,
                              hipStream_t stream)
{
    const int* an   = (const int*)d_in[0];
    const int* ct   = (const int*)d_in[1];
    const int* bt   = (const int*)d_in[2];
    const int* bd   = (const int*)d_in[3];
    const int* src  = (const int*)d_in[4];
    const int* dst  = (const int*)d_in[5];
    const int* gid  = (const int*)d_in[6];
    const float* emb_atom  = (const float*)d_in[8];
    const float* emb_chir  = (const float*)d_in[9];
    const float* edge_bond = (const float*)d_in[10];
    const float* edge_dir  = (const float*)d_in[11];
    const float* W1   = (const float*)d_in[12];
    const float* b1   = (const float*)d_in[13];
    const float* W2   = (const float*)d_in[14];
    const float* b2   = (const float*)d_in[15];
    const float* bn_g = (const float*)d_in[16];
    const float* bn_b = (const float*)d_in[17];
    const float* bn_m = (const float*)d_in[18];
    const float* bn_v = (const float*)d_in[19];
    const float* Wt   = (const float*)d_in[20];
    const float* btr  = (const float*)d_in[21];
    const float* Wh   = (const float*)d_in[22];
    const float* bh   = (const float*)d_in[23];
    const float* Wf   = (const float*)d_in[24];
    const float* bf   = (const float*)d_in[25];

    const long N = in_sizes[0];
    const long E = in_sizes[4];
    const int  G = NG;

    // ---- workspace (~249 MB): h | z | WbT1 | WbT2 | row_ptr | eidx ----
    char* base = (char*)d_ws;
    size_t off = 0;
    u16* h  = (u16*)(base + off);           off += (size_t)N * D_NODE * 2;
    u16* z  = (u16*)(base + off);           off += (size_t)N * D_NODE * 2;
    u16* WbT1 = (u16*)(base + off);         off += (size_t)NLAYER * 2 * PER1 * 2;
    u16* WbT2 = (u16*)(base + off);         off += (size_t)NLAYER * 2 * PER2 * 2;
    int* row_ptr = (int*)(base + off);      off += (((size_t)(N + 1) * 4) + 63) & ~(size_t)63;
    int* eidx = (int*)(base + off);
    // aliases into z (disjoint lifetimes: CSR build pre-embed; x1 post-layers)
    int* row_fill = (int*)z;
    int* bsum     = row_fill + N;
    float* x1     = (float*)z;

    const long nodeTot = N * 75;
    const int  blk = 256;
    const long nodeBlocks = (nodeTot + blk - 1) / blk;
    const int  SB = (int)((N + 1023) / 1024);

    // weights -> split bf16 (hi+lo), transposed, K-padded
    {
        long t1 = (long)NLAYER * PER1;
        wconv_split<<<(t1 + blk - 1) / blk, blk, 0, stream>>>(
            W1, WbT1, D_NODE, DHID, KP1, (long)PER1, t1);
        long t2 = (long)NLAYER * PER2;
        wconv_split<<<(t2 + blk - 1) / blk, blk, 0, stream>>>(
            W2, WbT2, DHID, D_NODE, KP2, (long)PER2, t2);
    }

    // CSR build (graph static across layers)
    zero_int_kernel<<<((int)N + blk - 1) / blk, blk, 0, stream>>>(row_fill, (int)N);
    count_kernel<<<((int)E + blk - 1) / blk, blk, 0, stream>>>(dst, row_fill, (int)E);
    scan1_kernel<<<SB, blk, 0, stream>>>(row_fill, bsum, (int)N);
    scan2_kernel<<<1, 64, 0, stream>>>(bsum, SB);
    scan3_kernel<<<SB, blk, 0, stream>>>(bsum, row_fill, row_ptr, (int)N, (int)E);
    fill_kernel<<<((int)E + blk - 1) / blk, blk, 0, stream>>>(dst, row_fill, eidx, (int)E);

    embed_kernel<<<nodeBlocks, blk, 0, stream>>>(an, ct, emb_atom, emb_chir, h, nodeTot);

    const int mlpBlocks = (int)((N + 63) / 64);
    for (int l = 0; l < NLAYER; ++l) {
        agg_kernel<<<nodeBlocks, blk, 0, stream>>>(
            h, src, bt, bd, row_ptr, eidx,
            edge_bond + (long)l * 6 * D_NODE,
            edge_dir  + (long)l * 3 * D_NODE,
            z, nodeTot);

        mlp_fused<<<mlpBlocks, 256, 0, stream>>>(
            z,
            WbT1 + (long)(2 * l) * PER1,
            WbT2 + (long)(2 * l) * PER2,
            b1 + (long)l * DHID, b2 + (long)l * D_NODE,
            bn_g + (long)l * D_NODE, bn_b + (long)l * D_NODE,
            bn_m + (long)l * D_NODE, bn_v + (long)l * D_NODE,
            h, (int)N, (l < NLAYER - 1) ? 1 : 0);
    }

    pool_head1<<<G, 256, 0, stream>>>(h, gid, (int)N, Wt, btr, x1);
    head2_kernel<<<G, 128, 0, stream>>>(x1, Wh, bh, Wf, bf, (float*)d_out, G);
}

// Round 16
// 4178.418 us; speedup vs baseline: 1.4055x; 1.0140x over previous
//
#include <hip/hip_runtime.h>
#include <hip/hip_bf16.h>

#define D_NODE 300
#define DHID   600
#define NLAYER 5
#define NG     8192
#define BN_EPS 1e-5f
#define KP1    320      // padded K for GEMM1 (300 -> 320)
#define KP2    608      // padded K for GEMM2 (600 -> 608)
#define PER1   (DHID * KP1)    // u16 per W1 plane
#define PER2   (D_NODE * KP2)  // u16 per W2 plane

typedef unsigned short u16;
typedef unsigned long long u64;
using f32x4   = __attribute__((ext_vector_type(4))) float;
using short8  = __attribute__((ext_vector_type(8))) short;
using short4v = __attribute__((ext_vector_type(4))) short;

// ---- bf16 helpers (RNE) ----
__device__ __forceinline__ float bf2f(u16 u) {
    union { unsigned int i; float f; } v; v.i = ((unsigned int)u) << 16; return v.f;
}
__device__ __forceinline__ u16 f2bf(float f) {
    union { float f; unsigned int i; } v; v.f = f;
    unsigned int x = v.i;
    return (u16)((x + 0x7FFFu + ((x >> 16) & 1u)) >> 16);
}

// ---------------- embed ----------------
__global__ __launch_bounds__(256) void embed_kernel(
    const int* __restrict__ an, const int* __restrict__ ct,
    const float* __restrict__ emb_atom, const float* __restrict__ emb_chir,
    u16* __restrict__ h, long total)
{
    long idx = (long)blockIdx.x * blockDim.x + threadIdx.x;
    if (idx >= total) return;
    int n = (int)(idx / 75);
    int c = (int)(idx % 75);
    int a = an[n], cc = ct[n];
    const float4 av = *(const float4*)&emb_atom[(long)a * D_NODE + c * 4];
    const float4 cv = *(const float4*)&emb_chir[(long)cc * D_NODE + c * 4];
    ushort4 o;
    o.x = f2bf(av.x + cv.x);
    o.y = f2bf(av.y + cv.y);
    o.z = f2bf(av.z + cv.z);
    o.w = f2bf(av.w + cv.w);
    *(ushort4*)&h[(long)n * D_NODE + c * 4] = o;
}

// ---- weight convert+split: [L][2][N][KP]; hi = bf16(W), lo = bf16(W - hi) ----
__global__ __launch_bounds__(256) void wconv_split(
    const float* __restrict__ W, u16* __restrict__ WbT,
    int K, int N, int KP, long per, long total)
{
    long idx = (long)blockIdx.x * blockDim.x + threadIdx.x;
    if (idx >= total) return;
    int l = (int)(idx / per);
    long r = idx % per;
    int n = (int)(r / KP);
    int k = (int)(r % KP);
    float v = (k < K) ? W[(long)l * K * N + (long)k * N + n] : 0.f;
    u16 hi = f2bf(v);
    float lo = v - bf2f(hi);
    WbT[(long)(2 * l) * per + r]     = hi;
    WbT[(long)(2 * l + 1) * per + r] = f2bf(lo);
}

// ---------------- CSR build ----------------
__global__ __launch_bounds__(256) void zero_int_kernel(int* __restrict__ p, int n)
{
    int i = blockIdx.x * blockDim.x + threadIdx.x;
    if (i < n) p[i] = 0;
}
__global__ __launch_bounds__(256) void count_kernel(
    const int* __restrict__ dst, int* __restrict__ cnt, int E)
{
    int e = blockIdx.x * blockDim.x + threadIdx.x;
    if (e < E) atomicAdd(&cnt[dst[e]], 1);
}
__global__ __launch_bounds__(256) void scan1_kernel(
    const int* __restrict__ cnt, int* __restrict__ bsum, int N)
{
    __shared__ int red[256];
    int b = blockIdx.x, t = threadIdx.x;
    int i0 = b * 1024 + t * 4;
    int s = 0;
    #pragma unroll
    for (int j = 0; j < 4; ++j) { int i = i0 + j; if (i < N) s += cnt[i]; }
    red[t] = s; __syncthreads();
    for (int off = 128; off > 0; off >>= 1) {
        if (t < off) red[t] += red[t + off];
        __syncthreads();
    }
    if (t == 0) bsum[b] = red[0];
}
__global__ void scan2_kernel(int* __restrict__ bsum, int nb)
{
    if (threadIdx.x == 0 && blockIdx.x == 0) {
        int run = 0;
        for (int b = 0; b < nb; ++b) { int v = bsum[b]; bsum[b] = run; run += v; }
    }
}
__global__ __launch_bounds__(256) void scan3_kernel(
    const int* __restrict__ bsum, int* __restrict__ cnt,
    int* __restrict__ row_ptr, int N, int E)
{
    __shared__ int sbuf[256];
    int b = blockIdx.x, t = threadIdx.x;
    int i0 = b * 1024 + t * 4;
    int v[4]; int s = 0;
    #pragma unroll
    for (int j = 0; j < 4; ++j) { int i = i0 + j; v[j] = (i < N) ? cnt[i] : 0; s += v[j]; }
    sbuf[t] = s; __syncthreads();
    for (int off = 1; off < 256; off <<= 1) {
        int add = (t >= off) ? sbuf[t - off] : 0;
        __syncthreads();
        sbuf[t] += add;
        __syncthreads();
    }
    int base = bsum[b] + sbuf[t] - s;
    #pragma unroll
    for (int j = 0; j < 4; ++j) {
        int i = i0 + j;
        if (i < N) { row_ptr[i] = base; cnt[i] = base; base += v[j]; }
    }
    if (b == 0 && t == 0) row_ptr[N] = E;
}
__global__ __launch_bounds__(256) void fill_kernel(
    const int* __restrict__ dst, int* __restrict__ fillp,
    int* __restrict__ eidx, int E)
{
    int e = blockIdx.x * blockDim.x + threadIdx.x;
    if (e < E) {
        int pos = atomicAdd(&fillp[dst[e]], 1);
        eidx[pos] = e;
    }
}

// ---------------- agg (gather): z[n] = h[n] + sum_in-edges (h[src]+eb+ed) ----------------
// Standalone: 58K blocks of pure TLP hide random-gather latency (R12 proved
// fusing this into the MLP starves it).
__global__ __launch_bounds__(256) void agg_kernel(
    const u16* __restrict__ h,
    const int* __restrict__ src, const int* __restrict__ bt, const int* __restrict__ bd,
    const int* __restrict__ row_ptr, const int* __restrict__ eidx,
    const float* __restrict__ ebond, const float* __restrict__ edir,
    u16* __restrict__ z, long total)
{
    long idx = (long)blockIdx.x * blockDim.x + threadIdx.x;
    if (idx >= total) return;
    int n = (int)(idx / 75);
    int c = (int)(idx % 75);
    const ushort4 hq = *(const ushort4*)&h[(long)n * D_NODE + c * 4];
    float a0 = bf2f(hq.x), a1 = bf2f(hq.y), a2 = bf2f(hq.z), a3 = bf2f(hq.w);
    int s0 = row_ptr[n], s1 = row_ptr[n + 1];
    for (int i = s0; i < s1; ++i) {
        int e = eidx[i];
        int s = src[e], b = bt[e], d = bd[e];
        const ushort4 hv = *(const ushort4*)&h[(long)s * D_NODE + c * 4];
        const float4 eb = *(const float4*)&ebond[(long)b * D_NODE + c * 4];
        const float4 ed = *(const float4*)&edir[(long)d * D_NODE + c * 4];
        a0 += bf2f(hv.x) + eb.x + ed.x;
        a1 += bf2f(hv.y) + eb.y + ed.y;
        a2 += bf2f(hv.z) + eb.z + ed.z;
        a3 += bf2f(hv.w) + eb.w + ed.w;
    }
    ushort4 o;
    o.x = f2bf(a0); o.y = f2bf(a1); o.z = f2bf(a2); o.w = f2bf(a3);
    *(ushort4*)&z[(long)n * D_NODE + c * 4] = o;
}

// ---------------- fused MLP v5: cross-phase overlap with Tc double-buffer ----------------
// Per tc iteration: P1(tc+1) and P2(tc) interleaved in ONE basic block (2:1
// chunk pattern), Tc[2] ping-pong. 6 barriers instead of 10; two independent
// MFMA/load streams per wave for the scheduler. Per-accumulator k-order
// unchanged -> bit-identical to R10/R15.

#define P1K(K0I) do { \
    const int _ko = (K0I) * 32; \
    short8 _a0 = *(const short8*)&As[ 0 + lrow][_ko + kg * 8]; \
    short8 _a1 = *(const short8*)&As[16 + lrow][_ko + kg * 8]; \
    short8 _a2 = *(const short8*)&As[32 + lrow][_ko + kg * 8]; \
    short8 _a3 = *(const short8*)&As[48 + lrow][_ko + kg * 8]; \
    short8 _wh0 = w1v[0] ? *(const short8*)(w1p[0] + _ko)        : zz; \
    short8 _wl0 = w1v[0] ? *(const short8*)(w1p[0] + PER1 + _ko) : zz; \
    short8 _wh1 = w1v[1] ? *(const short8*)(w1p[1] + _ko)        : zz; \
    short8 _wl1 = w1v[1] ? *(const short8*)(w1p[1] + PER1 + _ko) : zz; \
    __builtin_amdgcn_s_setprio(1); \
    p1[0][0] = __builtin_amdgcn_mfma_f32_16x16x32_bf16(_a0, _wh0, p1[0][0], 0, 0, 0); \
    p1[1][0] = __builtin_amdgcn_mfma_f32_16x16x32_bf16(_a1, _wh0, p1[1][0], 0, 0, 0); \
    p1[2][0] = __builtin_amdgcn_mfma_f32_16x16x32_bf16(_a2, _wh0, p1[2][0], 0, 0, 0); \
    p1[3][0] = __builtin_amdgcn_mfma_f32_16x16x32_bf16(_a3, _wh0, p1[3][0], 0, 0, 0); \
    p1[0][1] = __builtin_amdgcn_mfma_f32_16x16x32_bf16(_a0, _wh1, p1[0][1], 0, 0, 0); \
    p1[1][1] = __builtin_amdgcn_mfma_f32_16x16x32_bf16(_a1, _wh1, p1[1][1], 0, 0, 0); \
    p1[2][1] = __builtin_amdgcn_mfma_f32_16x16x32_bf16(_a2, _wh1, p1[2][1], 0, 0, 0); \
    p1[3][1] = __builtin_amdgcn_mfma_f32_16x16x32_bf16(_a3, _wh1, p1[3][1], 0, 0, 0); \
    p1[0][0] = __builtin_amdgcn_mfma_f32_16x16x32_bf16(_a0, _wl0, p1[0][0], 0, 0, 0); \
    p1[1][0] = __builtin_amdgcn_mfma_f32_16x16x32_bf16(_a1, _wl0, p1[1][0], 0, 0, 0); \
    p1[2][0] = __builtin_amdgcn_mfma_f32_16x16x32_bf16(_a2, _wl0, p1[2][0], 0, 0, 0); \
    p1[3][0] = __builtin_amdgcn_mfma_f32_16x16x32_bf16(_a3, _wl0, p1[3][0], 0, 0, 0); \
    p1[0][1] = __builtin_amdgcn_mfma_f32_16x16x32_bf16(_a0, _wl1, p1[0][1], 0, 0, 0); \
    p1[1][1] = __builtin_amdgcn_mfma_f32_16x16x32_bf16(_a1, _wl1, p1[1][1], 0, 0, 0); \
    p1[2][1] = __builtin_amdgcn_mfma_f32_16x16x32_bf16(_a2, _wl1, p1[2][1], 0, 0, 0); \
    p1[3][1] = __builtin_amdgcn_mfma_f32_16x16x32_bf16(_a3, _wl1, p1[3][1], 0, 0, 0); \
    __builtin_amdgcn_s_setprio(0); \
} while (0)

#define P2K(KS) do { \
    const int _kk = kbase + (KS) * 32; \
    short8 _t0 = *(const short8*)&Tc[rb][ 0 + lrow][(KS) * 32 + kg * 8]; \
    short8 _t1 = *(const short8*)&Tc[rb][16 + lrow][(KS) * 32 + kg * 8]; \
    short8 _t2 = *(const short8*)&Tc[rb][32 + lrow][(KS) * 32 + kg * 8]; \
    short8 _t3 = *(const short8*)&Tc[rb][48 + lrow][(KS) * 32 + kg * 8]; \
    short8 _w2h[5], _w2l[5]; \
    _Pragma("unroll") \
    for (int nf = 0; nf < 5; ++nf) { \
        _w2h[nf] = w2v[nf] ? *(const short8*)(w2p[nf] + _kk)        : zz; \
        _w2l[nf] = w2v[nf] ? *(const short8*)(w2p[nf] + PER2 + _kk) : zz; \
    } \
    __builtin_amdgcn_s_setprio(1); \
    _Pragma("unroll") \
    for (int nf = 0; nf < 5; ++nf) { \
        hacc[0][nf] = __builtin_amdgcn_mfma_f32_16x16x32_bf16(_t0, _w2h[nf], hacc[0][nf], 0, 0, 0); \
        hacc[1][nf] = __builtin_amdgcn_mfma_f32_16x16x32_bf16(_t1, _w2h[nf], hacc[1][nf], 0, 0, 0); \
        hacc[2][nf] = __builtin_amdgcn_mfma_f32_16x16x32_bf16(_t2, _w2h[nf], hacc[2][nf], 0, 0, 0); \
        hacc[3][nf] = __builtin_amdgcn_mfma_f32_16x16x32_bf16(_t3, _w2h[nf], hacc[3][nf], 0, 0, 0); \
    } \
    _Pragma("unroll") \
    for (int nf = 0; nf < 5; ++nf) { \
        hacc[0][nf] = __builtin_amdgcn_mfma_f32_16x16x32_bf16(_t0, _w2l[nf], hacc[0][nf], 0, 0, 0); \
        hacc[1][nf] = __builtin_amdgcn_mfma_f32_16x16x32_bf16(_t1, _w2l[nf], hacc[1][nf], 0, 0, 0); \
        hacc[2][nf] = __builtin_amdgcn_mfma_f32_16x16x32_bf16(_t2, _w2l[nf], hacc[2][nf], 0, 0, 0); \
        hacc[3][nf] = __builtin_amdgcn_mfma_f32_16x16x32_bf16(_t3, _w2l[nf], hacc[3][nf], 0, 0, 0); \
    } \
    __builtin_amdgcn_s_setprio(0); \
} while (0)

#define P1_SETUP(TCN) do { \
    const int _c0 = (TCN) * 128 + w * 32; \
    _Pragma("unroll") \
    for (int nf = 0; nf < 2; ++nf) { \
        int gn = _c0 + nf * 16 + lrow; \
        w1v[nf] = (gn < DHID); \
        w1p[nf] = W1T + (long)gn * KP1 + kg * 8; \
    } \
    _Pragma("unroll") \
    for (int m = 0; m < 4; ++m) \
        _Pragma("unroll") \
        for (int n = 0; n < 2; ++n) \
            p1[m][n] = (f32x4){0.f, 0.f, 0.f, 0.f}; \
} while (0)

#define TC_WRITE(TCN, WB) do { \
    const int _c0 = (TCN) * 128 + w * 32; \
    _Pragma("unroll") \
    for (int nf = 0; nf < 2; ++nf) { \
        int gn = _c0 + nf * 16 + lrow; \
        float _bias = w1v[nf] ? b1[gn] : 0.f; \
        _Pragma("unroll") \
        for (int m = 0; m < 4; ++m) \
            _Pragma("unroll") \
            for (int j = 0; j < 4; ++j) { \
                float _v = fmaxf(p1[m][nf][j] + _bias, 0.f); \
                Tc[WB][m * 16 + kg * 4 + j][w * 32 + nf * 16 + lrow] = f2bf(_v); \
            } \
    } \
} while (0)

__global__ __launch_bounds__(256, 2) void mlp_fused(
    const u16* __restrict__ Z,
    const u16* __restrict__ W1T,    // [600][320] hi, +PER1 lo
    const u16* __restrict__ W2T,    // [300][608] hi, +PER2 lo
    const float* __restrict__ b1, const float* __restrict__ b2,
    const float* __restrict__ bn_g, const float* __restrict__ bn_b,
    const float* __restrict__ bn_m, const float* __restrict__ bn_v,
    u16* __restrict__ Hout, int Nrows, int relu_out)
{
    __shared__ u16 As[64][328];      // 41,984 B
    __shared__ u16 Tc[2][64][136];   // 34,816 B  (total 76,800 -> 2 blocks/CU)
    const int tid  = threadIdx.x;
    const int lane = tid & 63;
    const int w    = tid >> 6;     // wave 0..3
    const int lrow = lane & 15;
    const int kg   = lane >> 4;    // 0..3
    const long r0  = (long)blockIdx.x * 64;
    const short8 zz = (short8){0,0,0,0,0,0,0,0};

    // stage Z tile: 64 rows x 320 k (zero-padded)
    for (int i = tid; i < 64 * 80; i += 256) {
        int r = i / 80, c4 = i % 80;
        short4v v = (short4v){0, 0, 0, 0};
        if (c4 < 75 && r0 + r < Nrows)
            v = *(const short4v*)&Z[(r0 + r) * D_NODE + c4 * 4];
        *(short4v*)&As[r][c4 * 4] = v;
    }
    __syncthreads();

    f32x4 hacc[4][5];
    #pragma unroll
    for (int m = 0; m < 4; ++m)
        #pragma unroll
        for (int n = 0; n < 5; ++n)
            hacc[m][n] = (f32x4){0.f, 0.f, 0.f, 0.f};

    // W2 per-wave output cols fixed across tc
    const u16* w2p[5]; bool w2v[5];
    #pragma unroll
    for (int nf = 0; nf < 5; ++nf) {
        int gn = w * 80 + nf * 16 + lrow;
        w2v[nf] = (gn < D_NODE);
        w2p[nf] = W2T + (long)gn * KP2 + kg * 8;
    }

    f32x4 p1[4][2];
    const u16* w1p[2]; bool w1v[2];

    // ---- prologue: P1(0) -> Tc[0] ----
    P1_SETUP(0);
    P1K(0); P1K(1); P1K(2); P1K(3); P1K(4);
    P1K(5); P1K(6); P1K(7); P1K(8); P1K(9);
    TC_WRITE(0, 0);
    __syncthreads();

    // ---- steady state: P1(tc+1) interleaved with P2(tc) ----
    for (int tc = 0; tc < 4; ++tc) {
        const int rb = tc & 1;
        const int kbase = tc * 128;
        const int tcn = tc + 1;
        P1_SETUP(tcn);
        P1K(0); P1K(1); P2K(0);
        P1K(2); P1K(3); P2K(1);
        P1K(4); P1K(5); P2K(2);
        P1K(6); P1K(7); P2K(3);
        P1K(8); P1K(9);
        TC_WRITE(tcn, rb ^ 1);
        __syncthreads();
    }

    // ---- peeled P2(4): k = 512..607 (3 ks), reads Tc[0] ----
    {
        const int rb = 0;
        const int kbase = 512;
        P2K(0); P2K(1); P2K(2);
    }

    // epilogue: bias + BN (+relu), store bf16
    #pragma unroll
    for (int nf = 0; nf < 5; ++nf) {
        int gn = w * 80 + nf * 16 + lrow;
        if (gn < D_NODE) {
            float bias = b2[gn];
            float sc = bn_g[gn] * rsqrtf(bn_v[gn] + BN_EPS);
            float mn = bn_m[gn], bb = bn_b[gn];
            #pragma unroll
            for (int m = 0; m < 4; ++m)
                #pragma unroll
                for (int j = 0; j < 4; ++j) {
                    long gr = r0 + m * 16 + kg * 4 + j;
                    if (gr < Nrows) {
                        float v = hacc[m][nf][j] + bias;
                        v = (v - mn) * sc + bb;
                        if (relu_out) v = fmaxf(v, 0.f);
                        Hout[gr * D_NODE + gn] = f2bf(v);
                    }
                }
        }
    }
}

// ---------------- fused pool (sorted gid) + Linear(300,256) ----------------
__device__ __forceinline__ int lower_bound(const int* __restrict__ a, int n, int key)
{
    int lo = 0, hi = n;
    while (lo < hi) { int mid = (lo + hi) >> 1; if (a[mid] < key) lo = mid + 1; else hi = mid; }
    return lo;
}

__global__ __launch_bounds__(256) void pool_head1(
    const u16* __restrict__ h, const int* __restrict__ gid, int N,
    const float* __restrict__ Wt, const float* __restrict__ bt,
    float* __restrict__ x1)
{
    __shared__ float xs[304];
    __shared__ int se[2];
    int g = blockIdx.x;
    int t = threadIdx.x;
    if (t == 0) se[0] = lower_bound(gid, N, g);
    if (t == 1) se[1] = lower_bound(gid, N, g + 1);
    __syncthreads();
    int start = se[0], end = se[1];
    float inv = (end > start) ? 1.0f / (float)(end - start) : 0.f;
    float a0 = 0.f, a1 = 0.f;
    for (int n = start; n < end; ++n) {
        const u16* hp = &h[(long)n * D_NODE];
        a0 += bf2f(hp[t]);
        if (t < 44) a1 += bf2f(hp[256 + t]);
    }
    xs[t] = a0 * inv;
    if (t < 44) xs[256 + t] = a1 * inv;
    __syncthreads();
    float acc = bt[t];
    for (int k = 0; k < D_NODE; ++k)
        acc = fmaf(xs[k], Wt[(long)k * 256 + t], acc);
    x1[(long)g * 256 + t] = acc;
}

// ---------------- head 2: Linear(256,128)+leaky, Linear(128,1) ----------------
__global__ __launch_bounds__(128) void head2_kernel(
    const float* __restrict__ x1,
    const float* __restrict__ Wh, const float* __restrict__ bh,
    const float* __restrict__ Wf, const float* __restrict__ bf,
    float* __restrict__ out, int G)
{
    __shared__ float xs[256];
    __shared__ float red[128];
    int g = blockIdx.x;
    int t = threadIdx.x;
    for (int i = t; i < 256; i += 128) xs[i] = x1[(long)g * 256 + i];
    __syncthreads();
    float acc = bh[t];
    for (int k = 0; k < 256; ++k)
        acc = fmaf(xs[k], Wh[(long)k * 128 + t], acc);
    acc = acc > 0.f ? acc : 0.01f * acc;
    red[t] = acc * Wf[t];
    __syncthreads();
    for (int s = 64; s > 0; s >>= 1) {
        if (t < s) red[t] += red[t + s];
        __syncthreads();
    }
    if (t == 0) out[g] = red[0] + bf[0];
}

extern "C" void kernel_launch(void* const* d_in, const int* in_sizes, int n_in,
                              void* d_out, int out_size, void* d_ws, size_t ws_size,
                              hipStream_t stream)
{
    const int* an   = (const int*)d_in[0];
    const int* ct   = (const int*)d_in[1];
    const int* bt   = (const int*)d_in[2];
    const int* bd   = (const int*)d_in[3];
    const int* src  = (const int*)d_in[4];
    const int* dst  = (const int*)d_in[5];
    const int* gid  = (const int*)d_in[6];
    const float* emb_atom  = (const float*)d_in[8];
    const float* emb_chir  = (const float*)d_in[9];
    const float* edge_bond = (const float*)d_in[10];
    const float* edge_dir  = (const float*)d_in[11];
    const float* W1   = (const float*)d_in[12];
    const float* b1   = (const float*)d_in[13];
    const float* W2   = (const float*)d_in[14];
    const float* b2   = (const float*)d_in[15];
    const float* bn_g = (const float*)d_in[16];
    const float* bn_b = (const float*)d_in[17];
    const float* bn_m = (const float*)d_in[18];
    const float* bn_v = (const float*)d_in[19];
    const float* Wt   = (const float*)d_in[20];
    const float* btr  = (const float*)d_in[21];
    const float* Wh   = (const float*)d_in[22];
    const float* bh   = (const float*)d_in[23];
    const float* Wf   = (const float*)d_in[24];
    const float* bf   = (const float*)d_in[25];

    const long N = in_sizes[0];
    const long E = in_sizes[4];
    const int  G = NG;

    // ---- workspace (~249 MB): h | z | WbT1 | WbT2 | row_ptr | eidx ----
    char* base = (char*)d_ws;
    size_t off = 0;
    u16* h  = (u16*)(base + off);           off += (size_t)N * D_NODE * 2;
    u16* z  = (u16*)(base + off);           off += (size_t)N * D_NODE * 2;
    u16* WbT1 = (u16*)(base + off);         off += (size_t)NLAYER * 2 * PER1 * 2;
    u16* WbT2 = (u16*)(base + off);         off += (size_t)NLAYER * 2 * PER2 * 2;
    int* row_ptr = (int*)(base + off);      off += (((size_t)(N + 1) * 4) + 63) & ~(size_t)63;
    int* eidx = (int*)(base + off);
    // aliases into z (disjoint lifetimes: CSR build pre-embed; x1 post-layers)
    int* row_fill = (int*)z;
    int* bsum     = row_fill + N;
    float* x1     = (float*)z;

    const long nodeTot = N * 75;
    const int  blk = 256;
    const long nodeBlocks = (nodeTot + blk - 1) / blk;
    const int  SB = (int)((N + 1023) / 1024);

    // weights -> split bf16 (hi+lo), transposed, K-padded
    {
        long t1 = (long)NLAYER * PER1;
        wconv_split<<<(t1 + blk - 1) / blk, blk, 0, stream>>>(
            W1, WbT1, D_NODE, DHID, KP1, (long)PER1, t1);
        long t2 = (long)NLAYER * PER2;
        wconv_split<<<(t2 + blk - 1) / blk, blk, 0, stream>>>(
            W2, WbT2, DHID, D_NODE, KP2, (long)PER2, t2);
    }

    // CSR build (graph static across layers)
    zero_int_kernel<<<((int)N + blk - 1) / blk, blk, 0, stream>>>(row_fill, (int)N);
    count_kernel<<<((int)E + blk - 1) / blk, blk, 0, stream>>>(dst, row_fill, (int)E);
    scan1_kernel<<<SB, blk, 0, stream>>>(row_fill, bsum, (int)N);
    scan2_kernel<<<1, 64, 0, stream>>>(bsum, SB);
    scan3_kernel<<<SB, blk, 0, stream>>>(bsum, row_fill, row_ptr, (int)N, (int)E);
    fill_kernel<<<((int)E + blk - 1) / blk, blk, 0, stream>>>(dst, row_fill, eidx, (int)E);

    embed_kernel<<<nodeBlocks, blk, 0, stream>>>(an, ct, emb_atom, emb_chir, h, nodeTot);

    const int mlpBlocks = (int)((N + 63) / 64);
    for (int l = 0; l < NLAYER; ++l) {
        agg_kernel<<<nodeBlocks, blk, 0, stream>>>(
            h, src, bt, bd, row_ptr, eidx,
            edge_bond + (long)l * 6 * D_NODE,
            edge_dir  + (long)l * 3 * D_NODE,
            z, nodeTot);

        mlp_fused<<<mlpBlocks, 256, 0, stream>>>(
            z,
            WbT1 + (long)(2 * l) * PER1,
            WbT2 + (long)(2 * l) * PER2,
            b1 + (long)l * DHID, b2 + (long)l * D_NODE,
            bn_g + (long)l * D_NODE, bn_b + (long)l * D_NODE,
            bn_m + (long)l * D_NODE, bn_v + (long)l * D_NODE,
            h, (int)N, (l < NLAYER - 1) ? 1 : 0);
    }

    pool_head1<<<G, 256, 0, stream>>>(h, gid, (int)N, Wt, btr, x1);
    head2_kernel<<<G, 128, 0, stream>>>(x1, Wh, bh, Wf, bf, (float*)d_out, G);
}